// Round 22
// baseline (107.115 us; speedup 1.0000x reference)
//
// v18.0 — proj inner loop: 16x16x32 -> 32x32x16 MFMA (2x FLOP/inst, LDS reads/wave
//         halved 20->10KB/iter, MFMA count 24->12). Fragment layouts identical to
//         session-verified attn_p1 usage. Staging/W-layout/copy-out/attn/merge
//         byte-identical to v16.1 (105.4us stable).
#include <hip/hip_runtime.h>
#include <stdint.h>

#define B_ 8
#define S_ 4096
#define E_ 1024
#define H_ 128
#define M_ (B_*S_)

typedef __attribute__((ext_vector_type(8))) short short8;
typedef __attribute__((ext_vector_type(4))) float f32x4;
typedef __attribute__((ext_vector_type(16))) float f32x16;

static constexpr float QSCALE = 0.08838834764831845f; // 1/sqrt(128)

__device__ __forceinline__ unsigned short f2bf(float f) {
    uint32_t u = __float_as_uint(f);
    u += 0x7fffu + ((u >> 16) & 1u);
    return (unsigned short)(u >> 16);
}

__device__ __forceinline__ uint32_t cvt_pk_bf16(float a, float b) {
    uint32_t r;
    asm("v_cvt_pk_bf16_f32 %0, %1, %2" : "=v"(r) : "v"(a), "v"(b));
    return r;
}

__device__ __forceinline__ float bf2f(uint32_t u) {
    return __uint_as_float(u << 16);
}

__device__ __forceinline__ void gl16(const void* g, void* s) {
    __builtin_amdgcn_global_load_lds(
        (const __attribute__((address_space(1))) unsigned int*)g,
        (__attribute__((address_space(3))) unsigned int*)s, 16, 0, 0);
}

// ---------------- W transpose + bf16 + BAKED v9-LDS layout (v16, unchanged) ----------------
__global__ __launch_bounds__(256)
void prep_w_kernel(const float* __restrict__ Wq, const float* __restrict__ Wk,
                   const float* __restrict__ Wv, unsigned short* __restrict__ Wt)
{
    int id = blockIdx.x*256 + threadIdx.x;
    int which = id >> 14;
    int rem = id & 16383;
    int h = rem >> 7, kc = rem & 127;
    const float* __restrict__ W = (which==0)?Wq:((which==1)?Wk:Wv);
    const float scale = (which==0)? QSCALE : 1.0f;
    uint32_t u[4];
    #pragma unroll
    for (int p=0;p<4;++p) {
        unsigned short a = f2bf(W[(size_t)(kc*8 + 2*p  )*H_ + h] * scale);
        unsigned short b = f2bf(W[(size_t)(kc*8 + 2*p+1)*H_ + h] * scale);
        u[p] = (uint32_t)a | ((uint32_t)b << 16);
    }
    uint4 v; v.x=u[0]; v.y=u[1]; v.z=u[2]; v.w=u[3];
    int gp = (kc >> 3)*128 + (((kc & 7) ^ (h & 7)) << 4);
    *(uint4*)((unsigned char*)Wt + (size_t)(which*H_ + h)*2048 + gp) = v;
}

// ---- proj staging: one BK=64 tile (x fp32 2x8KB subtiles + W bf16 48KB) ----
__device__ __forceinline__ void proj_stage(unsigned char* buf,
                                           const unsigned char* xb,
                                           const unsigned char* Wb,
                                           int i, int w, int l)
{
    #pragma unroll
    for (int j=0;j<8;++j) {
        int cb = (j*8 + w) * 1024;
        int A  = cb + (l << 4);
        if (cb < 16384) {                   // x: two [64][128B] subtiles (K halves)
            int sub = A >> 13;
            int A2  = A & 8191;
            int row = A2 >> 7, col = A2 & 127;
            gl16(xb + (size_t)row*4096 + i*256 + sub*128 + (col ^ ((row & 7) << 4)),
                 buf + cb);
        } else {                            // W: [384][128B], baked layout, linear rows
            int A2 = A - 16384;
            int wr = A2 >> 7, wc = A2 & 127;
            gl16(Wb + (size_t)wr*2048 + i*128 + wc, buf + cb);
        }
    }
}

// ---------------- FUSED QKV projection v8: 32x32x16 MFMA inner loop ----------------
// grid 512 (M_/64), block 512 (8 waves). wave w: rows (w&1)*32, cols (w>>1)*96.
__global__ __launch_bounds__(512)
void proj_kernel(const float* __restrict__ x, const unsigned short* __restrict__ Wt,
                 unsigned short* __restrict__ Qg, unsigned short* __restrict__ Kg,
                 unsigned short* __restrict__ Vtg)
{
    const int t = threadIdx.x;
    const int w = t >> 6, l = t & 63;
    const int hi = l >> 5, c31 = l & 31;
    const int rg = w & 1, cg = w >> 1;
    const int rb = blockIdx.x;
    const int row0 = rb * 64;

    __shared__ __align__(128) unsigned char smem[65536];  // x 16K + W 48K (single buf)
    unsigned short* epi = (unsigned short*)smem;          // epilogue [64][208] u16

    const unsigned char* xb = (const unsigned char*)x + (size_t)row0*4096;
    const unsigned char* Wb = (const unsigned char*)Wt;

    f32x16 acc[3];
    #pragma unroll
    for (int nt=0;nt<3;++nt)
        #pragma unroll
        for (int r=0;r<16;++r) acc[nt][r] = 0.f;

    proj_stage(smem, xb, Wb, 0, w, l);
    __syncthreads();

    const int xrow = rg*32 + c31;
    const int xsw  = (xrow & 7) << 4;

    for (int i=0; i<16; ++i) {
        const unsigned char* sX = smem;
        const unsigned char* sW = smem + 16384;

        #pragma unroll
        for (int ks=0; ks<4; ++ks) {
            // A-frag: x[xrow][k = ks*16 + hi*8 .. +8) fp32 -> bf16
            int k   = ks*16 + hi*8;
            int sub = k >> 5;
            int off = (k & 31) * 4;
            const unsigned char* base = sX + sub*8192 + xrow*128;
            float4 a0 = *(const float4*)(base + ((off     ) ^ xsw));
            float4 a1 = *(const float4*)(base + ((off + 16) ^ xsw));
            union { uint32_t u[4]; short8 s; } pa;
            pa.u[0] = cvt_pk_bf16(a0.x, a0.y);
            pa.u[1] = cvt_pk_bf16(a0.z, a0.w);
            pa.u[2] = cvt_pk_bf16(a1.x, a1.y);
            pa.u[3] = cvt_pk_bf16(a1.z, a1.w);
            short8 af = pa.s;

            #pragma unroll
            for (int nt=0; nt<3; ++nt) {
                int wr = cg*96 + nt*32 + c31;
                short8 bf = *(const short8*)(sW + wr*128 +
                              ((ks*32 + hi*16) ^ ((wr & 7) << 4)));
                acc[nt] = __builtin_amdgcn_mfma_f32_32x32x16_bf16(af, bf, acc[nt], 0,0,0);
            }
        }

        __syncthreads();               // all reads of buf done
        if (i+1 < 16) {
            proj_stage(smem, xb, Wb, i+1, w, l);
            __syncthreads();           // staged data visible (drains gl_lds)
        }
    }

    // ---------- epilogue: two LDS-staged passes (64 rows) ----------
    // C layout (session-verified): col n = c31, row m = (r&3)+8*(r>>2)+4*hi.
    const int bidx = rb >> 6;
    const int srow = (rb & 63) * 64;

    if (cg < 2) {
        #pragma unroll
        for (int nt=0;nt<3;++nt)
            #pragma unroll
            for (int r=0;r<16;++r) {
                int rowl = rg*32 + (r&3) + 8*(r>>2) + 4*hi;
                int col  = cg*96 + nt*32 + c31;
                epi[rowl*208 + col] = f2bf(acc[nt][r]);
            }
    }
    __syncthreads();
    #pragma unroll
    for (int i=0;i<2;++i) {
        int idx = i*512 + t;
        int row = idx >> 4, cc = idx & 15;
        uint4 v = *(const uint4*)((const unsigned char*)epi + row*416 + cc*16);
        *(uint4*)((unsigned char*)Qg + (size_t)(row0+row)*256 + cc*16) = v;
    }
    {
        int row = t >> 3, cc = t & 7;
        uint4 v = *(const uint4*)((const unsigned char*)epi + row*416 + 256 + cc*16);
        *(uint4*)((unsigned char*)Kg + (size_t)(row0+row)*256 + cc*16) = v;
    }
    __syncthreads();

    if (cg >= 2) {
        #pragma unroll
        for (int nt=0;nt<3;++nt)
            #pragma unroll
            for (int r=0;r<16;++r) {
                int rowl = rg*32 + (r&3) + 8*(r>>2) + 4*hi;
                int col  = (cg-2)*96 + nt*32 + c31;
                epi[rowl*208 + col] = f2bf(acc[nt][r]);
            }
    }
    __syncthreads();
    {
        int row = t >> 3, cc = t & 7;
        uint4 v = *(const uint4*)((const unsigned char*)epi + row*416 + cc*16);
        *(uint4*)((unsigned char*)Kg + (size_t)(row0+row)*256 + 128 + cc*16) = v;
    }
    #pragma unroll
    for (int i=0;i<2;++i) {
        int idx = i*512 + t;
        int h = idx >> 3, sc = idx & 7;
        uint32_t u[4];
        #pragma unroll
        for (int p=0;p<4;++p) {
            unsigned short a = epi[(sc*8 + 2*p    )*208 + 64 + h];
            unsigned short b = epi[(sc*8 + 2*p + 1)*208 + 64 + h];
            u[p] = (uint32_t)a | ((uint32_t)b << 16);
        }
        uint4 v; v.x=u[0]; v.y=u[1]; v.z=u[2]; v.w=u[3];
        *(uint4*)(Vtg + (size_t)(bidx*H_ + h)*S_ + srow + sc*8) = v;
    }
}

// ---- async stage of one 64-key tile (K 16KB + Vt 16KB) via global_load_lds ----
__device__ __forceinline__ void stage_tile(unsigned char* buf,
                                           const unsigned char* Kb,
                                           const unsigned char* Vb,
                                           int kt, int w, int l)
{
    unsigned char* sVb = buf + 16384;
    #pragma unroll
    for (int j=0;j<2;++j) {
        int A = w*2048 + j*1024 + (l<<4);
        int krow = A >> 8;
        int kin  = A & 255;
        gl16(Kb + (size_t)kt*16384 + krow*256 + (kin ^ ((krow&7)<<4)),
             buf + w*2048 + j*1024);
        int h   = A >> 7;
        int vin = A & 127;
        gl16(Vb + (size_t)h*8192 + (size_t)kt*128 + (vin ^ ((h&7)<<4)),
             sVb + w*2048 + j*1024);
    }
}

// ---------------- attn pass1: paired q-tiles, 4-way parity split; bf16 partials ----------------
__global__ __launch_bounds__(512, 2)
void attn_p1(const unsigned short* __restrict__ Qg,
             const unsigned short* __restrict__ Kg,
             const unsigned short* __restrict__ Vtg,
             unsigned short* __restrict__ Pp, float* __restrict__ Ml)
{
    const int t    = threadIdx.x;
    const int w    = t >> 6;
    const int l    = t & 63;
    const int hi   = l >> 5;
    const int c31  = l & 31;
    const int gid  = blockIdx.x;
    const int b    = gid & 7;
    const int rr   = gid >> 3;
    const int c4   = rr & 3;      // key-parity chunk (mod 4)
    const int pr   = rr >> 2;     // pair index 0..7

    __shared__ __align__(128) unsigned char smem[65536];  // 2 x (K 16K + V 16K)

    const size_t bbase = (size_t)b * S_ * H_;
    const unsigned char* Kb = (const unsigned char*)(Kg + bbase);
    const unsigned char* Vb = (const unsigned char*)(Vtg + (size_t)b*H_*S_);
    const int swzq = (c31 & 7) << 4;

    int cur = 0;
    for (int ph = 0; ph < 2; ++ph) {
        const int qt   = ph ? (15 - pr) : pr;
        const int q0   = qt * 256;
        const int qw0  = q0 + w*32;
        const int qrow = qw0 + c31;
        const int nkt  = 4*(qt+1);

        short8 qf[8];
        {
            const unsigned short* qp = Qg + bbase + (size_t)qrow * H_;
            #pragma unroll
            for (int ks=0; ks<8; ++ks)
                qf[ks] = *(const short8*)(qp + ks*16 + hi*8);
        }

        f32x16 oacc[4];
        #pragma unroll
        for (int ht=0; ht<4; ++ht)
            #pragma unroll
            for (int r=0; r<16; ++r) oacc[ht][r] = 0.f;
        float mrun = -1e30f, lrun = 0.f;

        stage_tile(smem + cur*32768, Kb, Vb, c4, w, l);
        __syncthreads();

        for (int kt = c4; kt < nkt; kt += 4) {
            const bool pre = (kt+4 < nkt);
            if (pre) stage_tile(smem + (cur^1)*32768, Kb, Vb, kt+4, w, l);

            if (kt*64 <= qw0 + 31) {
                const unsigned char* sK = smem + cur*32768;
                const unsigned char* sV = sK + 16384;

                f32x16 sacc[2];
                #pragma unroll
                for (int st=0; st<2; ++st)
                    #pragma unroll
                    for (int r=0; r<16; ++r) sacc[st][r] = 0.f;
                #pragma unroll
                for (int st=0; st<2; ++st) {
                    int krow = st*32 + c31;
                    #pragma unroll
                    for (int ks=0; ks<8; ++ks) {
                        short8 kf = *(const short8*)(sK + krow*256 + ((ks*32 + hi*16) ^ swzq));
                        sacc[st] = __builtin_amdgcn_mfma_f32_32x32x16_bf16(kf, qf[ks], sacc[st], 0,0,0);
                    }
                }

                if (kt*64 + 63 > qw0) {
                    #pragma unroll
                    for (int st=0; st<2; ++st)
                        #pragma unroll
                        for (int r=0; r<16; ++r) {
                            int key = kt*64 + st*32 + (r&3) + 8*(r>>2) + 4*hi;
                            if (key > qrow) sacc[st][r] = -1e30f;
                        }
                }

                float pmax = -1e30f;
                #pragma unroll
                for (int st=0; st<2; ++st)
                    #pragma unroll
                    for (int r=0; r<16; ++r) pmax = fmaxf(pmax, sacc[st][r]);
                pmax = fmaxf(pmax, __shfl_xor(pmax, 32, 64));

                if (!__all(pmax - mrun <= 8.0f)) {
                    float mnew = fmaxf(mrun, pmax);
                    float alpha = __expf(mrun - mnew);
                    #pragma unroll
                    for (int ht=0; ht<4; ++ht)
                        #pragma unroll
                        for (int r=0; r<16; ++r) oacc[ht][r] *= alpha;
                    lrun *= alpha;
                    mrun = mnew;
                }

                float p[2][16];
                float psum = 0.f;
                #pragma unroll
                for (int st=0; st<2; ++st)
                    #pragma unroll
                    for (int r=0; r<16; ++r) {
                        float e = __expf(sacc[st][r] - mrun);
                        p[st][r] = e;
                        psum += e;
                    }
                psum += __shfl_xor(psum, 32, 64);
                lrun += psum;

                short8 pf[4];
                #pragma unroll
                for (int st=0; st<2; ++st) {
                    uint32_t A0 = cvt_pk_bf16(p[st][0],  p[st][1]);
                    uint32_t A1 = cvt_pk_bf16(p[st][2],  p[st][3]);
                    uint32_t B0 = cvt_pk_bf16(p[st][4],  p[st][5]);
                    uint32_t B1 = cvt_pk_bf16(p[st][6],  p[st][7]);
                    uint32_t C0 = cvt_pk_bf16(p[st][8],  p[st][9]);
                    uint32_t C1 = cvt_pk_bf16(p[st][10], p[st][11]);
                    uint32_t D0 = cvt_pk_bf16(p[st][12], p[st][13]);
                    uint32_t D1 = cvt_pk_bf16(p[st][14], p[st][15]);
                    {
                        uint32_t x0 = hi ? A0 : B0;
                        uint32_t x1 = hi ? A1 : B1;
                        uint32_t y0 = (uint32_t)__shfl_xor((int)x0, 32, 64);
                        uint32_t y1 = (uint32_t)__shfl_xor((int)x1, 32, 64);
                        union { uint32_t u[4]; short8 s; } uu;
                        uu.u[0] = hi ? y0 : A0;
                        uu.u[1] = hi ? y1 : A1;
                        uu.u[2] = hi ? B0 : y0;
                        uu.u[3] = hi ? B1 : y1;
                        pf[st*2] = uu.s;
                    }
                    {
                        uint32_t x0 = hi ? C0 : D0;
                        uint32_t x1 = hi ? C1 : D1;
                        uint32_t y0 = (uint32_t)__shfl_xor((int)x0, 32, 64);
                        uint32_t y1 = (uint32_t)__shfl_xor((int)x1, 32, 64);
                        union { uint32_t u[4]; short8 s; } uu;
                        uu.u[0] = hi ? y0 : C0;
                        uu.u[1] = hi ? y1 : C1;
                        uu.u[2] = hi ? D0 : y0;
                        uu.u[3] = hi ? D1 : y1;
                        pf[st*2+1] = uu.s;
                    }
                }

                #pragma unroll
                for (int sl=0; sl<4; ++sl) {
                    #pragma unroll
                    for (int ht=0; ht<4; ++ht) {
                        int h = ht*32 + c31;
                        short8 vf = *(const short8*)(sV + h*128 + ((sl*32 + hi*16) ^ swzq));
                        oacc[ht] = __builtin_amdgcn_mfma_f32_32x32x16_bf16(vf, pf[sl], oacc[ht], 0,0,0);
                    }
                }
            }

            __syncthreads();   // drains global_load_lds (vmcnt) + phase separation
            if (pre) cur ^= 1;
        }

        // epilogue: write partial O as bf16 + (m, l) fp32
        unsigned short* Prow = Pp + (size_t)c4*((size_t)M_*H_) + bbase + (size_t)qrow*H_;
        #pragma unroll
        for (int ht=0; ht<4; ++ht)
            #pragma unroll
            for (int k=0; k<4; ++k) {
                uint2 o;
                o.x = cvt_pk_bf16(oacc[ht][4*k+0], oacc[ht][4*k+1]);
                o.y = cvt_pk_bf16(oacc[ht][4*k+2], oacc[ht][4*k+3]);
                *(uint2*)(Prow + ht*32 + 8*k + 4*hi) = o;
            }
        if (hi == 0) {
            float2 ml2; ml2.x = mrun; ml2.y = lrun;
            *(float2*)(Ml + ((size_t)c4*M_ + (size_t)b*S_ + qrow)*2) = ml2;
        }
    }
}

// ---------------- merge: renormalize 4 bf16 partials ----------------
__global__ __launch_bounds__(256)
void attn_merge(const unsigned short* __restrict__ Pp, const float* __restrict__ Ml,
                float* __restrict__ Out)
{
    int gid = blockIdx.x*256 + threadIdx.x;
    int q  = gid >> 5;
    int h4 = gid & 31;

    float m0 = Ml[((size_t)0*M_ + q)*2], l0 = Ml[((size_t)0*M_ + q)*2 + 1];
    float m1 = Ml[((size_t)1*M_ + q)*2], l1 = Ml[((size_t)1*M_ + q)*2 + 1];
    float m2 = Ml[((size_t)2*M_ + q)*2], l2 = Ml[((size_t)2*M_ + q)*2 + 1];
    float m3 = Ml[((size_t)3*M_ + q)*2], l3 = Ml[((size_t)3*M_ + q)*2 + 1];

    float M = fmaxf(fmaxf(m0, m1), fmaxf(m2, m3));
    float w0 = __expf(m0 - M), w1 = __expf(m1 - M);
    float w2 = __expf(m2 - M), w3 = __expf(m3 - M);
    float L = w0*l0 + w1*l1 + w2*l2 + w3*l3;

    uint2 u0 = *(const uint2*)(Pp + (size_t)0*((size_t)M_*H_) + (size_t)q*H_ + h4*4);
    uint2 u1 = *(const uint2*)(Pp + (size_t)1*((size_t)M_*H_) + (size_t)q*H_ + h4*4);
    uint2 u2 = *(const uint2*)(Pp + (size_t)2*((size_t)M_*H_) + (size_t)q*H_ + h4*4);
    uint2 u3 = *(const uint2*)(Pp + (size_t)3*((size_t)M_*H_) + (size_t)q*H_ + h4*4);
    float inv = 1.0f / L;
    float4 o;
    o.x = (w0*bf2f(u0.x & 0xffffu) + w1*bf2f(u1.x & 0xffffu)
         + w2*bf2f(u2.x & 0xffffu) + w3*bf2f(u3.x & 0xffffu)) * inv;
    o.y = (w0*bf2f(u0.x >> 16)     + w1*bf2f(u1.x >> 16)
         + w2*bf2f(u2.x >> 16)     + w3*bf2f(u3.x >> 16)) * inv;
    o.z = (w0*bf2f(u0.y & 0xffffu) + w1*bf2f(u1.y & 0xffffu)
         + w2*bf2f(u2.y & 0xffffu) + w3*bf2f(u3.y & 0xffffu)) * inv;
    o.w = (w0*bf2f(u0.y >> 16)     + w1*bf2f(u1.y >> 16)
         + w2*bf2f(u2.y >> 16)     + w3*bf2f(u3.y >> 16)) * inv;
    *(float4*)(Out + (size_t)q*H_ + h4*4) = o;
}

// ---------------- fallback (v3 single-pass attn) if ws too small ----------------
__global__ __launch_bounds__(128, 1)
void attn_fb(const unsigned short* __restrict__ Qg,
             const unsigned short* __restrict__ Kg,
             const unsigned short* __restrict__ Vtg,
             float* __restrict__ Out)
{
    const int t   = threadIdx.x;
    const int w   = t >> 6;
    const int l   = t & 63;
    const int hi  = l >> 5;
    const int c31 = l & 31;
    const int qt  = (S_/64 - 1) - blockIdx.x;
    const int b   = blockIdx.y;
    const int q0  = qt * 64;
    const int qrow = q0 + w*32 + c31;

    __shared__ __align__(128) unsigned char sK[16384];
    __shared__ __align__(128) unsigned char sV[16384];

    const size_t bbase = (size_t)b * S_ * H_;

    short8 qf[8];
    {
        const unsigned short* qp = Qg + bbase + (size_t)qrow * H_;
        #pragma unroll
        for (int ks=0; ks<8; ++ks)
            qf[ks] = *(const short8*)(qp + ks*16 + hi*8);
    }

    f32x16 oacc[4];
    #pragma unroll
    for (int ht=0; ht<4; ++ht)
        #pragma unroll
        for (int r=0; r<16; ++r) oacc[ht][r] = 0.f;
    float mrun = -1e30f, lrun = 0.f;

    const unsigned char* Kb = (const unsigned char*)(Kg + bbase);
    const unsigned char* Vb = (const unsigned char*)(Vtg + (size_t)b*H_*S_);
    const int swzq = (c31 & 7) << 4;

    for (int kt=0; kt<=qt; ++kt) {
        __syncthreads();
        #pragma unroll
        for (int i=0;i<8;++i) {
            int c = i*128 + t;
            int row = c >> 4, cb = (c & 15) * 16;
            *(uint4*)(sK + row*256 + (cb ^ ((row&7)<<4))) =
                *(const uint4*)(Kb + (size_t)(kt*64 + row)*256 + cb);
        }
        #pragma unroll
        for (int i=0;i<8;++i) {
            int c = i*128 + t;
            int h = c >> 3, cb = (c & 7) * 16;
            *(uint4*)(sV + h*128 + (cb ^ ((h&7)<<4))) =
                *(const uint4*)(Vb + (size_t)h*(S_*2) + kt*128 + cb);
        }
        __syncthreads();

        f32x16 sacc[2];
        #pragma unroll
        for (int st=0; st<2; ++st)
            #pragma unroll
            for (int r=0; r<16; ++r) sacc[st][r] = 0.f;
        #pragma unroll
        for (int st=0; st<2; ++st) {
            int krow = st*32 + c31;
            #pragma unroll
            for (int ks=0; ks<8; ++ks) {
                short8 kf = *(const short8*)(sK + krow*256 + ((ks*32 + hi*16) ^ swzq));
                sacc[st] = __builtin_amdgcn_mfma_f32_32x32x16_bf16(kf, qf[ks], sacc[st], 0,0,0);
            }
        }

        if (kt == qt) {
            #pragma unroll
            for (int st=0; st<2; ++st)
                #pragma unroll
                for (int r=0; r<16; ++r) {
                    int key = q0 + st*32 + (r&3) + 8*(r>>2) + 4*hi;
                    if (key > qrow) sacc[st][r] = -1e30f;
                }
        }

        float pmax = -1e30f;
        #pragma unroll
        for (int st=0; st<2; ++st)
            #pragma unroll
            for (int r=0; r<16; ++r) pmax = fmaxf(pmax, sacc[st][r]);
        pmax = fmaxf(pmax, __shfl_xor(pmax, 32, 64));

        if (!__all(pmax - mrun <= 8.0f)) {
            float mnew = fmaxf(mrun, pmax);
            float alpha = __expf(mrun - mnew);
            #pragma unroll
            for (int ht=0; ht<4; ++ht)
                #pragma unroll
                for (int r=0; r<16; ++r) oacc[ht][r] *= alpha;
            lrun *= alpha;
            mrun = mnew;
        }

        float p[2][16];
        float psum = 0.f;
        #pragma unroll
        for (int st=0; st<2; ++st)
            #pragma unroll
            for (int r=0; r<16; ++r) {
                float e = __expf(sacc[st][r] - mrun);
                p[st][r] = e;
                psum += e;
            }
        psum += __shfl_xor(psum, 32, 64);
        lrun += psum;

        short8 pf[4];
        #pragma unroll
        for (int st=0; st<2; ++st) {
            uint32_t A0 = cvt_pk_bf16(p[st][0],  p[st][1]);
            uint32_t A1 = cvt_pk_bf16(p[st][2],  p[st][3]);
            uint32_t B0 = cvt_pk_bf16(p[st][4],  p[st][5]);
            uint32_t B1 = cvt_pk_bf16(p[st][6],  p[st][7]);
            uint32_t C0 = cvt_pk_bf16(p[st][8],  p[st][9]);
            uint32_t C1 = cvt_pk_bf16(p[st][10], p[st][11]);
            uint32_t D0 = cvt_pk_bf16(p[st][12], p[st][13]);
            uint32_t D1 = cvt_pk_bf16(p[st][14], p[st][15]);
            {
                uint32_t x0 = hi ? A0 : B0;
                uint32_t x1 = hi ? A1 : B1;
                uint32_t y0 = (uint32_t)__shfl_xor((int)x0, 32, 64);
                uint32_t y1 = (uint32_t)__shfl_xor((int)x1, 32, 64);
                union { uint32_t u[4]; short8 s; } uu;
                uu.u[0] = hi ? y0 : A0;
                uu.u[1] = hi ? y1 : A1;
                uu.u[2] = hi ? B0 : y0;
                uu.u[3] = hi ? B1 : y1;
                pf[st*2] = uu.s;
            }
            {
                uint32_t x0 = hi ? C0 : D0;
                uint32_t x1 = hi ? C1 : D1;
                uint32_t y0 = (uint32_t)__shfl_xor((int)x0, 32, 64);
                uint32_t y1 = (uint32_t)__shfl_xor((int)x1, 32, 64);
                union { uint32_t u[4]; short8 s; } uu;
                uu.u[0] = hi ? y0 : C0;
                uu.u[1] = hi ? y1 : C1;
                uu.u[2] = hi ? D0 : y0;
                uu.u[3] = hi ? D1 : y1;
                pf[st*2+1] = uu.s;
            }
        }

        #pragma unroll
        for (int sl=0; sl<4; ++sl) {
            #pragma unroll
            for (int ht=0; ht<4; ++ht) {
                int h = ht*32 + c31;
                short8 vf = *(const short8*)(sV + h*128 + ((sl*32 + hi*16) ^ swzq));
                oacc[ht] = __builtin_amdgcn_mfma_f32_32x32x16_bf16(vf, pf[sl], oacc[ht], 0,0,0);
            }
        }
    }

    float linv = 1.0f / lrun;
    float* Op = Out + bbase + (size_t)qrow * H_;
    #pragma unroll
    for (int ht=0; ht<4; ++ht)
        #pragma unroll
        for (int k=0; k<4; ++k) {
            float4 o;
            o.x = oacc[ht][4*k+0] * linv;
            o.y = oacc[ht][4*k+1] * linv;
            o.z = oacc[ht][4*k+2] * linv;
            o.w = oacc[ht][4*k+3] * linv;
            *(float4*)(Op + ht*32 + 8*k + 4*hi) = o;
        }
}

extern "C" void kernel_launch(void* const* d_in, const int* in_sizes, int n_in,
                              void* d_out, int out_size, void* d_ws, size_t ws_size,
                              hipStream_t stream) {
    const float* x  = (const float*)d_in[0];
    const float* Wq = (const float*)d_in[1];
    const float* Wk = (const float*)d_in[2];
    const float* Wv = (const float*)d_in[3];

    unsigned char* ws = (unsigned char*)d_ws;
    unsigned short* Wt  = (unsigned short*)ws;                          // 768 KB @ 0
    unsigned short* Qg  = (unsigned short*)(ws + 1048576u);             // 8 MB
    unsigned short* Kg  = (unsigned short*)(ws + 9437184u);             // 8 MB
    unsigned short* Vtg = (unsigned short*)(ws + 17825792u);            // 8 MB
    unsigned short* Pp  = (unsigned short*)(ws + 26214400u);            // 32 MB (4 chunks bf16)
    float* Ml = (float*)(ws + 59768832u);                               // 1 MB
    const size_t NEED = 60817408u;

    prep_w_kernel<<<192, 256, 0, stream>>>(Wq, Wk, Wv, Wt);
    proj_kernel<<<512, 512, 0, stream>>>(x, Wt, Qg, Kg, Vtg);

    if (ws_size >= NEED) {
        attn_p1<<<256, 512, 0, stream>>>(Qg, Kg, Vtg, Pp, Ml);
        attn_merge<<<4096, 256, 0, stream>>>(Pp, Ml, (float*)d_out);
    } else {
        dim3 ga(S_/64, B_);
        attn_fb<<<ga, 128, 0, stream>>>(Qg, Kg, Vtg, (float*)d_out);
    }
}

// Round 23
// 105.273 us; speedup vs baseline: 1.0175x; 1.0175x over previous
//
// v16.2 — FINAL LOCK: byte-identical to r19/r21 measured-best build (105.4us, 2x reproduced).
//         r22 closed the proj ablation map: ~77us invariant to BK/buffering/occupancy/
//         vmcnt/MFMA-shape/LDS-volume -> stage-barrier family constant. 14.3x vs baseline.
#include <hip/hip_runtime.h>
#include <stdint.h>

#define B_ 8
#define S_ 4096
#define E_ 1024
#define H_ 128
#define M_ (B_*S_)

typedef __attribute__((ext_vector_type(8))) short short8;
typedef __attribute__((ext_vector_type(4))) float f32x4;
typedef __attribute__((ext_vector_type(16))) float f32x16;

static constexpr float QSCALE = 0.08838834764831845f; // 1/sqrt(128)

__device__ __forceinline__ unsigned short f2bf(float f) {
    uint32_t u = __float_as_uint(f);
    u += 0x7fffu + ((u >> 16) & 1u);
    return (unsigned short)(u >> 16);
}

__device__ __forceinline__ uint32_t cvt_pk_bf16(float a, float b) {
    uint32_t r;
    asm("v_cvt_pk_bf16_f32 %0, %1, %2" : "=v"(r) : "v"(a), "v"(b));
    return r;
}

__device__ __forceinline__ float bf2f(uint32_t u) {
    return __uint_as_float(u << 16);
}

__device__ __forceinline__ void gl16(const void* g, void* s) {
    __builtin_amdgcn_global_load_lds(
        (const __attribute__((address_space(1))) unsigned int*)g,
        (__attribute__((address_space(3))) unsigned int*)s, 16, 0, 0);
}

// ---------------- W transpose + bf16 + BAKED v9-LDS layout ----------------
__global__ __launch_bounds__(256)
void prep_w_kernel(const float* __restrict__ Wq, const float* __restrict__ Wk,
                   const float* __restrict__ Wv, unsigned short* __restrict__ Wt)
{
    int id = blockIdx.x*256 + threadIdx.x;
    int which = id >> 14;
    int rem = id & 16383;
    int h = rem >> 7, kc = rem & 127;
    const float* __restrict__ W = (which==0)?Wq:((which==1)?Wk:Wv);
    const float scale = (which==0)? QSCALE : 1.0f;
    uint32_t u[4];
    #pragma unroll
    for (int p=0;p<4;++p) {
        unsigned short a = f2bf(W[(size_t)(kc*8 + 2*p  )*H_ + h] * scale);
        unsigned short b = f2bf(W[(size_t)(kc*8 + 2*p+1)*H_ + h] * scale);
        u[p] = (uint32_t)a | ((uint32_t)b << 16);
    }
    uint4 v; v.x=u[0]; v.y=u[1]; v.z=u[2]; v.w=u[3];
    int gp = (kc >> 3)*128 + (((kc & 7) ^ (h & 7)) << 4);
    *(uint4*)((unsigned char*)Wt + (size_t)(which*H_ + h)*2048 + gp) = v;
}

// ---- proj staging: one BK=64 tile (x fp32 2x8KB subtiles + W bf16 48KB) ----
__device__ __forceinline__ void proj_stage(unsigned char* buf,
                                           const unsigned char* xb,
                                           const unsigned char* Wb,
                                           int i, int w, int l)
{
    #pragma unroll
    for (int j=0;j<8;++j) {
        int cb = (j*8 + w) * 1024;
        int A  = cb + (l << 4);
        if (cb < 16384) {                   // x: two [64][128B] subtiles (K halves)
            int sub = A >> 13;
            int A2  = A & 8191;
            int row = A2 >> 7, col = A2 & 127;
            gl16(xb + (size_t)row*4096 + i*256 + sub*128 + (col ^ ((row & 7) << 4)),
                 buf + cb);
        } else {                            // W: [384][128B], baked layout, linear rows
            int A2 = A - 16384;
            int wr = A2 >> 7, wc = A2 & 127;
            gl16(Wb + (size_t)wr*2048 + i*128 + wc, buf + cb);
        }
    }
}

// ---------------- FUSED QKV projection v6: BK=64, single-buf, 2 blk/CU ----------------
__global__ __launch_bounds__(512)
void proj_kernel(const float* __restrict__ x, const unsigned short* __restrict__ Wt,
                 unsigned short* __restrict__ Qg, unsigned short* __restrict__ Kg,
                 unsigned short* __restrict__ Vtg)
{
    const int t = threadIdx.x;
    const int w = t >> 6, l = t & 63;
    const int grp = l >> 4, li = l & 15;
    const int rg = w & 1, cg = w >> 1;
    const int rb = blockIdx.x;
    const int row0 = rb * 64;

    __shared__ __align__(128) unsigned char smem[65536];  // x 16K + W 48K (single buf)
    unsigned short* epi = (unsigned short*)smem;          // epilogue [64][208] u16

    const unsigned char* xb = (const unsigned char*)x + (size_t)row0*4096;
    const unsigned char* Wb = (const unsigned char*)Wt;

    f32x4 acc[2][6];
    const f32x4 zz = {0.f,0.f,0.f,0.f};
    #pragma unroll
    for (int mt=0;mt<2;++mt)
        #pragma unroll
        for (int nt=0;nt<6;++nt) acc[mt][nt] = zz;

    proj_stage(smem, xb, Wb, 0, w, l);
    __syncthreads();

    for (int i=0; i<16; ++i) {
        const unsigned char* sX = smem;
        const unsigned char* sW = smem + 16384;

        #pragma unroll
        for (int ks=0;ks<2;++ks) {
            short8 af[2];
            #pragma unroll
            for (int mt=0;mt<2;++mt) {
                int row = rg*32 + mt*16 + li;
                int sw = (row & 7) << 4;
                float4 a0 = *(const float4*)(sX + ks*8192 + row*128 + ((grp*32     ) ^ sw));
                float4 a1 = *(const float4*)(sX + ks*8192 + row*128 + ((grp*32 + 16) ^ sw));
                union { uint32_t u[4]; short8 s; } pa;
                pa.u[0] = cvt_pk_bf16(a0.x, a0.y);
                pa.u[1] = cvt_pk_bf16(a0.z, a0.w);
                pa.u[2] = cvt_pk_bf16(a1.x, a1.y);
                pa.u[3] = cvt_pk_bf16(a1.z, a1.w);
                af[mt] = pa.s;
            }
            #pragma unroll
            for (int nt=0;nt<6;++nt) {
                int wr = cg*96 + nt*16 + li;
                short8 bf = *(const short8*)(sW + wr*128 + ((ks*64 + grp*16) ^ ((wr & 7) << 4)));
                acc[0][nt] = __builtin_amdgcn_mfma_f32_16x16x32_bf16(af[0], bf, acc[0][nt], 0,0,0);
                acc[1][nt] = __builtin_amdgcn_mfma_f32_16x16x32_bf16(af[1], bf, acc[1][nt], 0,0,0);
            }
        }

        __syncthreads();               // all reads of buf done
        if (i+1 < 16) {
            proj_stage(smem, xb, Wb, i+1, w, l);
            __syncthreads();           // staged data visible (drains gl_lds)
        }
    }

    // ---------- epilogue: two LDS-staged passes (64 rows) ----------
    const int bidx = rb >> 6;
    const int srow = (rb & 63) * 64;

    if (cg < 2) {
        #pragma unroll
        for (int mt=0;mt<2;++mt)
            #pragma unroll
            for (int nt=0;nt<6;++nt)
                #pragma unroll
                for (int r=0;r<4;++r) {
                    int rowl = rg*32 + mt*16 + grp*4 + r;
                    int col  = cg*96 + nt*16 + li;
                    epi[rowl*208 + col] = f2bf(acc[mt][nt][r]);
                }
    }
    __syncthreads();
    #pragma unroll
    for (int i=0;i<2;++i) {
        int idx = i*512 + t;
        int row = idx >> 4, cc = idx & 15;
        uint4 v = *(const uint4*)((const unsigned char*)epi + row*416 + cc*16);
        *(uint4*)((unsigned char*)Qg + (size_t)(row0+row)*256 + cc*16) = v;
    }
    {
        int row = t >> 3, cc = t & 7;
        uint4 v = *(const uint4*)((const unsigned char*)epi + row*416 + 256 + cc*16);
        *(uint4*)((unsigned char*)Kg + (size_t)(row0+row)*256 + cc*16) = v;
    }
    __syncthreads();

    if (cg >= 2) {
        #pragma unroll
        for (int mt=0;mt<2;++mt)
            #pragma unroll
            for (int nt=0;nt<6;++nt)
                #pragma unroll
                for (int r=0;r<4;++r) {
                    int rowl = rg*32 + mt*16 + grp*4 + r;
                    int col  = (cg-2)*96 + nt*16 + li;
                    epi[rowl*208 + col] = f2bf(acc[mt][nt][r]);
                }
    }
    __syncthreads();
    {
        int row = t >> 3, cc = t & 7;
        uint4 v = *(const uint4*)((const unsigned char*)epi + row*416 + cc*16);
        *(uint4*)((unsigned char*)Kg + (size_t)(row0+row)*256 + 128 + cc*16) = v;
    }
    #pragma unroll
    for (int i=0;i<2;++i) {
        int idx = i*512 + t;
        int h = idx >> 3, sc = idx & 7;
        uint32_t u[4];
        #pragma unroll
        for (int p=0;p<4;++p) {
            unsigned short a = epi[(sc*8 + 2*p    )*208 + 64 + h];
            unsigned short b = epi[(sc*8 + 2*p + 1)*208 + 64 + h];
            u[p] = (uint32_t)a | ((uint32_t)b << 16);
        }
        uint4 v; v.x=u[0]; v.y=u[1]; v.z=u[2]; v.w=u[3];
        *(uint4*)(Vtg + (size_t)(bidx*H_ + h)*S_ + srow + sc*8) = v;
    }
}

// ---- async stage of one 64-key tile (K 16KB + Vt 16KB) via global_load_lds ----
__device__ __forceinline__ void stage_tile(unsigned char* buf,
                                           const unsigned char* Kb,
                                           const unsigned char* Vb,
                                           int kt, int w, int l)
{
    unsigned char* sVb = buf + 16384;
    #pragma unroll
    for (int j=0;j<2;++j) {
        int A = w*2048 + j*1024 + (l<<4);
        int krow = A >> 8;
        int kin  = A & 255;
        gl16(Kb + (size_t)kt*16384 + krow*256 + (kin ^ ((krow&7)<<4)),
             buf + w*2048 + j*1024);
        int h   = A >> 7;
        int vin = A & 127;
        gl16(Vb + (size_t)h*8192 + (size_t)kt*128 + (vin ^ ((h&7)<<4)),
             sVb + w*2048 + j*1024);
    }
}

// ---------------- attn pass1: paired q-tiles, 4-way parity split; bf16 partials ----------------
__global__ __launch_bounds__(512, 2)
void attn_p1(const unsigned short* __restrict__ Qg,
             const unsigned short* __restrict__ Kg,
             const unsigned short* __restrict__ Vtg,
             unsigned short* __restrict__ Pp, float* __restrict__ Ml)
{
    const int t    = threadIdx.x;
    const int w    = t >> 6;
    const int l    = t & 63;
    const int hi   = l >> 5;
    const int c31  = l & 31;
    const int gid  = blockIdx.x;
    const int b    = gid & 7;
    const int rr   = gid >> 3;
    const int c4   = rr & 3;      // key-parity chunk (mod 4)
    const int pr   = rr >> 2;     // pair index 0..7

    __shared__ __align__(128) unsigned char smem[65536];  // 2 x (K 16K + V 16K)

    const size_t bbase = (size_t)b * S_ * H_;
    const unsigned char* Kb = (const unsigned char*)(Kg + bbase);
    const unsigned char* Vb = (const unsigned char*)(Vtg + (size_t)b*H_*S_);
    const int swzq = (c31 & 7) << 4;

    int cur = 0;
    for (int ph = 0; ph < 2; ++ph) {
        const int qt   = ph ? (15 - pr) : pr;
        const int q0   = qt * 256;
        const int qw0  = q0 + w*32;
        const int qrow = qw0 + c31;
        const int nkt  = 4*(qt+1);

        short8 qf[8];
        {
            const unsigned short* qp = Qg + bbase + (size_t)qrow * H_;
            #pragma unroll
            for (int ks=0; ks<8; ++ks)
                qf[ks] = *(const short8*)(qp + ks*16 + hi*8);
        }

        f32x16 oacc[4];
        #pragma unroll
        for (int ht=0; ht<4; ++ht)
            #pragma unroll
            for (int r=0; r<16; ++r) oacc[ht][r] = 0.f;
        float mrun = -1e30f, lrun = 0.f;

        stage_tile(smem + cur*32768, Kb, Vb, c4, w, l);
        __syncthreads();

        for (int kt = c4; kt < nkt; kt += 4) {
            const bool pre = (kt+4 < nkt);
            if (pre) stage_tile(smem + (cur^1)*32768, Kb, Vb, kt+4, w, l);

            if (kt*64 <= qw0 + 31) {
                const unsigned char* sK = smem + cur*32768;
                const unsigned char* sV = sK + 16384;

                f32x16 sacc[2];
                #pragma unroll
                for (int st=0; st<2; ++st)
                    #pragma unroll
                    for (int r=0; r<16; ++r) sacc[st][r] = 0.f;
                #pragma unroll
                for (int st=0; st<2; ++st) {
                    int krow = st*32 + c31;
                    #pragma unroll
                    for (int ks=0; ks<8; ++ks) {
                        short8 kf = *(const short8*)(sK + krow*256 + ((ks*32 + hi*16) ^ swzq));
                        sacc[st] = __builtin_amdgcn_mfma_f32_32x32x16_bf16(kf, qf[ks], sacc[st], 0,0,0);
                    }
                }

                if (kt*64 + 63 > qw0) {
                    #pragma unroll
                    for (int st=0; st<2; ++st)
                        #pragma unroll
                        for (int r=0; r<16; ++r) {
                            int key = kt*64 + st*32 + (r&3) + 8*(r>>2) + 4*hi;
                            if (key > qrow) sacc[st][r] = -1e30f;
                        }
                }

                float pmax = -1e30f;
                #pragma unroll
                for (int st=0; st<2; ++st)
                    #pragma unroll
                    for (int r=0; r<16; ++r) pmax = fmaxf(pmax, sacc[st][r]);
                pmax = fmaxf(pmax, __shfl_xor(pmax, 32, 64));

                if (!__all(pmax - mrun <= 8.0f)) {
                    float mnew = fmaxf(mrun, pmax);
                    float alpha = __expf(mrun - mnew);
                    #pragma unroll
                    for (int ht=0; ht<4; ++ht)
                        #pragma unroll
                        for (int r=0; r<16; ++r) oacc[ht][r] *= alpha;
                    lrun *= alpha;
                    mrun = mnew;
                }

                float p[2][16];
                float psum = 0.f;
                #pragma unroll
                for (int st=0; st<2; ++st)
                    #pragma unroll
                    for (int r=0; r<16; ++r) {
                        float e = __expf(sacc[st][r] - mrun);
                        p[st][r] = e;
                        psum += e;
                    }
                psum += __shfl_xor(psum, 32, 64);
                lrun += psum;

                short8 pf[4];
                #pragma unroll
                for (int st=0; st<2; ++st) {
                    uint32_t A0 = cvt_pk_bf16(p[st][0],  p[st][1]);
                    uint32_t A1 = cvt_pk_bf16(p[st][2],  p[st][3]);
                    uint32_t B0 = cvt_pk_bf16(p[st][4],  p[st][5]);
                    uint32_t B1 = cvt_pk_bf16(p[st][6],  p[st][7]);
                    uint32_t C0 = cvt_pk_bf16(p[st][8],  p[st][9]);
                    uint32_t C1 = cvt_pk_bf16(p[st][10], p[st][11]);
                    uint32_t D0 = cvt_pk_bf16(p[st][12], p[st][13]);
                    uint32_t D1 = cvt_pk_bf16(p[st][14], p[st][15]);
                    {
                        uint32_t x0 = hi ? A0 : B0;
                        uint32_t x1 = hi ? A1 : B1;
                        uint32_t y0 = (uint32_t)__shfl_xor((int)x0, 32, 64);
                        uint32_t y1 = (uint32_t)__shfl_xor((int)x1, 32, 64);
                        union { uint32_t u[4]; short8 s; } uu;
                        uu.u[0] = hi ? y0 : A0;
                        uu.u[1] = hi ? y1 : A1;
                        uu.u[2] = hi ? B0 : y0;
                        uu.u[3] = hi ? B1 : y1;
                        pf[st*2] = uu.s;
                    }
                    {
                        uint32_t x0 = hi ? C0 : D0;
                        uint32_t x1 = hi ? C1 : D1;
                        uint32_t y0 = (uint32_t)__shfl_xor((int)x0, 32, 64);
                        uint32_t y1 = (uint32_t)__shfl_xor((int)x1, 32, 64);
                        union { uint32_t u[4]; short8 s; } uu;
                        uu.u[0] = hi ? y0 : C0;
                        uu.u[1] = hi ? y1 : C1;
                        uu.u[2] = hi ? D0 : y0;
                        uu.u[3] = hi ? D1 : y1;
                        pf[st*2+1] = uu.s;
                    }
                }

                #pragma unroll
                for (int sl=0; sl<4; ++sl) {
                    #pragma unroll
                    for (int ht=0; ht<4; ++ht) {
                        int h = ht*32 + c31;
                        short8 vf = *(const short8*)(sV + h*128 + ((sl*32 + hi*16) ^ swzq));
                        oacc[ht] = __builtin_amdgcn_mfma_f32_32x32x16_bf16(vf, pf[sl], oacc[ht], 0,0,0);
                    }
                }
            }

            __syncthreads();   // drains global_load_lds (vmcnt) + phase separation
            if (pre) cur ^= 1;
        }

        // epilogue: write partial O as bf16 + (m, l) fp32
        unsigned short* Prow = Pp + (size_t)c4*((size_t)M_*H_) + bbase + (size_t)qrow*H_;
        #pragma unroll
        for (int ht=0; ht<4; ++ht)
            #pragma unroll
            for (int k=0; k<4; ++k) {
                uint2 o;
                o.x = cvt_pk_bf16(oacc[ht][4*k+0], oacc[ht][4*k+1]);
                o.y = cvt_pk_bf16(oacc[ht][4*k+2], oacc[ht][4*k+3]);
                *(uint2*)(Prow + ht*32 + 8*k + 4*hi) = o;
            }
        if (hi == 0) {
            float2 ml2; ml2.x = mrun; ml2.y = lrun;
            *(float2*)(Ml + ((size_t)c4*M_ + (size_t)b*S_ + qrow)*2) = ml2;
        }
    }
}

// ---------------- merge: renormalize 4 bf16 partials ----------------
__global__ __launch_bounds__(256)
void attn_merge(const unsigned short* __restrict__ Pp, const float* __restrict__ Ml,
                float* __restrict__ Out)
{
    int gid = blockIdx.x*256 + threadIdx.x;
    int q  = gid >> 5;
    int h4 = gid & 31;

    float m0 = Ml[((size_t)0*M_ + q)*2], l0 = Ml[((size_t)0*M_ + q)*2 + 1];
    float m1 = Ml[((size_t)1*M_ + q)*2], l1 = Ml[((size_t)1*M_ + q)*2 + 1];
    float m2 = Ml[((size_t)2*M_ + q)*2], l2 = Ml[((size_t)2*M_ + q)*2 + 1];
    float m3 = Ml[((size_t)3*M_ + q)*2], l3 = Ml[((size_t)3*M_ + q)*2 + 1];

    float M = fmaxf(fmaxf(m0, m1), fmaxf(m2, m3));
    float w0 = __expf(m0 - M), w1 = __expf(m1 - M);
    float w2 = __expf(m2 - M), w3 = __expf(m3 - M);
    float L = w0*l0 + w1*l1 + w2*l2 + w3*l3;

    uint2 u0 = *(const uint2*)(Pp + (size_t)0*((size_t)M_*H_) + (size_t)q*H_ + h4*4);
    uint2 u1 = *(const uint2*)(Pp + (size_t)1*((size_t)M_*H_) + (size_t)q*H_ + h4*4);
    uint2 u2 = *(const uint2*)(Pp + (size_t)2*((size_t)M_*H_) + (size_t)q*H_ + h4*4);
    uint2 u3 = *(const uint2*)(Pp + (size_t)3*((size_t)M_*H_) + (size_t)q*H_ + h4*4);
    float inv = 1.0f / L;
    float4 o;
    o.x = (w0*bf2f(u0.x & 0xffffu) + w1*bf2f(u1.x & 0xffffu)
         + w2*bf2f(u2.x & 0xffffu) + w3*bf2f(u3.x & 0xffffu)) * inv;
    o.y = (w0*bf2f(u0.x >> 16)     + w1*bf2f(u1.x >> 16)
         + w2*bf2f(u2.x >> 16)     + w3*bf2f(u3.x >> 16)) * inv;
    o.z = (w0*bf2f(u0.y & 0xffffu) + w1*bf2f(u1.y & 0xffffu)
         + w2*bf2f(u2.y & 0xffffu) + w3*bf2f(u3.y & 0xffffu)) * inv;
    o.w = (w0*bf2f(u0.y >> 16)     + w1*bf2f(u1.y >> 16)
         + w2*bf2f(u2.y >> 16)     + w3*bf2f(u3.y >> 16)) * inv;
    *(float4*)(Out + (size_t)q*H_ + h4*4) = o;
}

// ---------------- fallback (v3 single-pass attn) if ws too small ----------------
__global__ __launch_bounds__(128, 1)
void attn_fb(const unsigned short* __restrict__ Qg,
             const unsigned short* __restrict__ Kg,
             const unsigned short* __restrict__ Vtg,
             float* __restrict__ Out)
{
    const int t   = threadIdx.x;
    const int w   = t >> 6;
    const int l   = t & 63;
    const int hi  = l >> 5;
    const int c31 = l & 31;
    const int qt  = (S_/64 - 1) - blockIdx.x;
    const int b   = blockIdx.y;
    const int q0  = qt * 64;
    const int qrow = q0 + w*32 + c31;

    __shared__ __align__(128) unsigned char sK[16384];
    __shared__ __align__(128) unsigned char sV[16384];

    const size_t bbase = (size_t)b * S_ * H_;

    short8 qf[8];
    {
        const unsigned short* qp = Qg + bbase + (size_t)qrow * H_;
        #pragma unroll
        for (int ks=0; ks<8; ++ks)
            qf[ks] = *(const short8*)(qp + ks*16 + hi*8);
    }

    f32x16 oacc[4];
    #pragma unroll
    for (int ht=0; ht<4; ++ht)
        #pragma unroll
        for (int r=0; r<16; ++r) oacc[ht][r] = 0.f;
    float mrun = -1e30f, lrun = 0.f;

    const unsigned char* Kb = (const unsigned char*)(Kg + bbase);
    const unsigned char* Vb = (const unsigned char*)(Vtg + (size_t)b*H_*S_);
    const int swzq = (c31 & 7) << 4;

    for (int kt=0; kt<=qt; ++kt) {
        __syncthreads();
        #pragma unroll
        for (int i=0;i<8;++i) {
            int c = i*128 + t;
            int row = c >> 4, cb = (c & 15) * 16;
            *(uint4*)(sK + row*256 + (cb ^ ((row&7)<<4))) =
                *(const uint4*)(Kb + (size_t)(kt*64 + row)*256 + cb);
        }
        #pragma unroll
        for (int i=0;i<8;++i) {
            int c = i*128 + t;
            int h = c >> 3, cb = (c & 7) * 16;
            *(uint4*)(sV + h*128 + (cb ^ ((h&7)<<4))) =
                *(const uint4*)(Vb + (size_t)h*(S_*2) + kt*128 + cb);
        }
        __syncthreads();

        f32x16 sacc[2];
        #pragma unroll
        for (int st=0; st<2; ++st)
            #pragma unroll
            for (int r=0; r<16; ++r) sacc[st][r] = 0.f;
        #pragma unroll
        for (int st=0; st<2; ++st) {
            int krow = st*32 + c31;
            #pragma unroll
            for (int ks=0; ks<8; ++ks) {
                short8 kf = *(const short8*)(sK + krow*256 + ((ks*32 + hi*16) ^ swzq));
                sacc[st] = __builtin_amdgcn_mfma_f32_32x32x16_bf16(kf, qf[ks], sacc[st], 0,0,0);
            }
        }

        if (kt == qt) {
            #pragma unroll
            for (int st=0; st<2; ++st)
                #pragma unroll
                for (int r=0; r<16; ++r) {
                    int key = q0 + st*32 + (r&3) + 8*(r>>2) + 4*hi;
                    if (key > qrow) sacc[st][r] = -1e30f;
                }
        }

        float pmax = -1e30f;
        #pragma unroll
        for (int st=0; st<2; ++st)
            #pragma unroll
            for (int r=0; r<16; ++r) pmax = fmaxf(pmax, sacc[st][r]);
        pmax = fmaxf(pmax, __shfl_xor(pmax, 32, 64));

        if (!__all(pmax - mrun <= 8.0f)) {
            float mnew = fmaxf(mrun, pmax);
            float alpha = __expf(mrun - mnew);
            #pragma unroll
            for (int ht=0; ht<4; ++ht)
                #pragma unroll
                for (int r=0; r<16; ++r) oacc[ht][r] *= alpha;
            lrun *= alpha;
            mrun = mnew;
        }

        float p[2][16];
        float psum = 0.f;
        #pragma unroll
        for (int st=0; st<2; ++st)
            #pragma unroll
            for (int r=0; r<16; ++r) {
                float e = __expf(sacc[st][r] - mrun);
                p[st][r] = e;
                psum += e;
            }
        psum += __shfl_xor(psum, 32, 64);
        lrun += psum;

        short8 pf[4];
        #pragma unroll
        for (int st=0; st<2; ++st) {
            uint32_t A0 = cvt_pk_bf16(p[st][0],  p[st][1]);
            uint32_t A1 = cvt_pk_bf16(p[st][2],  p[st][3]);
            uint32_t B0 = cvt_pk_bf16(p[st][4],  p[st][5]);
            uint32_t B1 = cvt_pk_bf16(p[st][6],  p[st][7]);
            uint32_t C0 = cvt_pk_bf16(p[st][8],  p[st][9]);
            uint32_t C1 = cvt_pk_bf16(p[st][10], p[st][11]);
            uint32_t D0 = cvt_pk_bf16(p[st][12], p[st][13]);
            uint32_t D1 = cvt_pk_bf16(p[st][14], p[st][15]);
            {
                uint32_t x0 = hi ? A0 : B0;
                uint32_t x1 = hi ? A1 : B1;
                uint32_t y0 = (uint32_t)__shfl_xor((int)x0, 32, 64);
                uint32_t y1 = (uint32_t)__shfl_xor((int)x1, 32, 64);
                union { uint32_t u[4]; short8 s; } uu;
                uu.u[0] = hi ? y0 : A0;
                uu.u[1] = hi ? y1 : A1;
                uu.u[2] = hi ? B0 : y0;
                uu.u[3] = hi ? B1 : y1;
                pf[st*2] = uu.s;
            }
            {
                uint32_t x0 = hi ? C0 : D0;
                uint32_t x1 = hi ? C1 : D1;
                uint32_t y0 = (uint32_t)__shfl_xor((int)x0, 32, 64);
                uint32_t y1 = (uint32_t)__shfl_xor((int)x1, 32, 64);
                union { uint32_t u[4]; short8 s; } uu;
                uu.u[0] = hi ? y0 : C0;
                uu.u[1] = hi ? y1 : C1;
                uu.u[2] = hi ? D0 : y0;
                uu.u[3] = hi ? D1 : y1;
                pf[st*2+1] = uu.s;
            }
        }

        #pragma unroll
        for (int sl=0; sl<4; ++sl) {
            #pragma unroll
            for (int ht=0; ht<4; ++ht) {
                int h = ht*32 + c31;
                short8 vf = *(const short8*)(sV + h*128 + ((sl*32 + hi*16) ^ swzq));
                oacc[ht] = __builtin_amdgcn_mfma_f32_32x32x16_bf16(vf, pf[sl], oacc[ht], 0,0,0);
            }
        }
    }

    float linv = 1.0f / lrun;
    float* Op = Out + bbase + (size_t)qrow * H_;
    #pragma unroll
    for (int ht=0; ht<4; ++ht)
        #pragma unroll
        for (int k=0; k<4; ++k) {
            float4 o;
            o.x = oacc[ht][4*k+0] * linv;
            o.y = oacc[ht][4*k+1] * linv;
            o.z = oacc[ht][4*k+2] * linv;
            o.w = oacc[ht][4*k+3] * linv;
            *(float4*)(Op + ht*32 + 8*k + 4*hi) = o;
        }
}

extern "C" void kernel_launch(void* const* d_in, const int* in_sizes, int n_in,
                              void* d_out, int out_size, void* d_ws, size_t ws_size,
                              hipStream_t stream) {
    const float* x  = (const float*)d_in[0];
    const float* Wq = (const float*)d_in[1];
    const float* Wk = (const float*)d_in[2];
    const float* Wv = (const float*)d_in[3];

    unsigned char* ws = (unsigned char*)d_ws;
    unsigned short* Wt  = (unsigned short*)ws;                          // 768 KB @ 0
    unsigned short* Qg  = (unsigned short*)(ws + 1048576u);             // 8 MB
    unsigned short* Kg  = (unsigned short*)(ws + 9437184u);             // 8 MB
    unsigned short* Vtg = (unsigned short*)(ws + 17825792u);            // 8 MB
    unsigned short* Pp  = (unsigned short*)(ws + 26214400u);            // 32 MB (4 chunks bf16)
    float* Ml = (float*)(ws + 59768832u);                               // 1 MB
    const size_t NEED = 60817408u;

    prep_w_kernel<<<192, 256, 0, stream>>>(Wq, Wk, Wv, Wt);
    proj_kernel<<<512, 512, 0, stream>>>(x, Wt, Qg, Kg, Vtg);

    if (ws_size >= NEED) {
        attn_p1<<<256, 512, 0, stream>>>(Qg, Kg, Vtg, Pp, Ml);
        attn_merge<<<4096, 256, 0, stream>>>(Pp, Ml, (float*)d_out);
    } else {
        dim3 ga(S_/64, B_);
        attn_fb<<<ga, 128, 0, stream>>>(Qg, Kg, Vtg, (float*)d_out);
    }
}